// Round 4
// baseline (389.241 us; speedup 1.0000x reference)
//
#include <hip/hip_runtime.h>
#include <cstddef>

// B=2,H=16 -> BH=32
#define BH    32
#define NSEQ  4096
#define MFEAT 256
#define CHUNK 128
#define NCH   32
#define SROW  65          // 64 d-rows + 1 z-row
#define SPITCH (SROW*256) // 16640 f16 per (bh,chunk) state

#define SCALE 0.35355339059327373f  // 64^-0.25

typedef unsigned int uint_t;
typedef _Float16 half_t;
typedef __attribute__((ext_vector_type(8))) _Float16 half8;
typedef __attribute__((ext_vector_type(4))) float f32x4;

__device__ __forceinline__ f32x4 mfma16(half8 a, half8 b, f32x4 c) {
  return __builtin_amdgcn_mfma_f32_16x16x32_f16(a, b, c, 0, 0, 0);
}
__device__ __forceinline__ uint_t enc_f(float x) {
  uint_t u = __float_as_uint(x);
  return (u & 0x80000000u) ? ~u : (u | 0x80000000u);
}
__device__ __forceinline__ float dec_f(uint_t u) {
  u = (u & 0x80000000u) ? (u ^ 0x80000000u) : ~u;
  return __uint_as_float(u);
}
__device__ __forceinline__ half8 cvt_h8(float4 a, float4 b) {
  half8 h;
  h[0] = (half_t)a.x; h[1] = (half_t)a.y; h[2] = (half_t)a.z; h[3] = (half_t)a.w;
  h[4] = (half_t)b.x; h[5] = (half_t)b.y; h[6] = (half_t)b.z; h[7] = (half_t)b.w;
  return h;
}

__global__ void k_init(uint_t* kmax) { *kmax = enc_f(-__builtin_inff()); }

// ============================================================================
// k_maxes: 64 rows of q AND k per block, reg a-frags, omega in LDS, 1 barrier.
//   q: rowmQ[row] = max_m (q_s @ w^T)   (norm cancels in per-row max)
//   k: atomicMax(kmax, max(proj - 0.5|x|^2))
// LDS 37 KB -> 4 blocks/CU.
// ============================================================================
__global__ __launch_bounds__(256, 4) void k_maxes(
    const float* __restrict__ q, const float* __restrict__ kx,
    const float* __restrict__ omega, float* __restrict__ rowmQ,
    uint_t* __restrict__ kmax)
{
  __shared__ half_t Wl[256 * 72];
  __shared__ float nrm[64];
  __shared__ float red[4];

  const int tid = threadIdx.x;
  const int lane = tid & 63;
  const int w = tid >> 6;
  const int lc = lane & 15, rg = lane >> 4, koff = rg * 8;
  const size_t rowbase = (size_t)blockIdx.x * 64;

  // omega fp32 -> f16 LDS
  for (int l = tid; l < 4096; l += 256) {
    int m = l >> 4, d4 = (l & 15) * 4;
    float4 o = *(const float4*)(omega + m * 64 + d4);
    half_t* p = &Wl[m * 72 + d4];
    p[0] = (half_t)o.x; p[1] = (half_t)o.y; p[2] = (half_t)o.z; p[3] = (half_t)o.w;
  }
  // q,k a-frags direct to regs; k row norms via shfl
  half8 aq[2], akf[2];
  {
    const float* qp = q + (rowbase + w * 16 + lc) * 64 + koff;
    const float* kp = kx + (rowbase + w * 16 + lc) * 64 + koff;
    float pn = 0.f;
    #pragma unroll
    for (int ks = 0; ks < 2; ks++) {
      float4 a = *(const float4*)(qp + ks * 32);
      float4 b = *(const float4*)(qp + ks * 32 + 4);
      a.x *= SCALE; a.y *= SCALE; a.z *= SCALE; a.w *= SCALE;
      b.x *= SCALE; b.y *= SCALE; b.z *= SCALE; b.w *= SCALE;
      aq[ks] = cvt_h8(a, b);
      float4 c = *(const float4*)(kp + ks * 32);
      float4 d = *(const float4*)(kp + ks * 32 + 4);
      c.x *= SCALE; c.y *= SCALE; c.z *= SCALE; c.w *= SCALE;
      d.x *= SCALE; d.y *= SCALE; d.z *= SCALE; d.w *= SCALE;
      pn += c.x * c.x + c.y * c.y + c.z * c.z + c.w * c.w
          + d.x * d.x + d.y * d.y + d.z * d.z + d.w * d.w;
      akf[ks] = cvt_h8(c, d);
    }
    pn += __shfl_xor(pn, 16, 64);
    pn += __shfl_xor(pn, 32, 64);
    if (rg == 0) nrm[w * 16 + lc] = 0.5f * pn;
  }
  __syncthreads();

  // proj q in two 8-ct chunks -> per-row max
  float mrow[4] = {-3.4e38f, -3.4e38f, -3.4e38f, -3.4e38f};
  #pragma unroll
  for (int hh = 0; hh < 2; hh++) {
    f32x4 acc[8];
    #pragma unroll
    for (int c = 0; c < 8; c++) acc[c] = (f32x4){0.f, 0.f, 0.f, 0.f};
    #pragma unroll
    for (int ks = 0; ks < 2; ks++)
      #pragma unroll
      for (int c = 0; c < 8; c++) {
        half8 b = *(const half8*)&Wl[((hh * 8 + c) * 16 + lc) * 72 + ks * 32 + koff];
        acc[c] = mfma16(aq[ks], b, acc[c]);
      }
    #pragma unroll
    for (int c = 0; c < 8; c++)
      #pragma unroll
      for (int r = 0; r < 4; r++) mrow[r] = fmaxf(mrow[r], acc[c][r]);
  }
  #pragma unroll
  for (int r = 0; r < 4; r++) {
    float m0 = mrow[r];
    m0 = fmaxf(m0, __shfl_xor(m0, 1, 64));
    m0 = fmaxf(m0, __shfl_xor(m0, 2, 64));
    m0 = fmaxf(m0, __shfl_xor(m0, 4, 64));
    m0 = fmaxf(m0, __shfl_xor(m0, 8, 64));
    if (lc == 0) rowmQ[rowbase + w * 16 + rg * 4 + r] = m0;
  }

  // proj k -> global max
  float hn[4];
  #pragma unroll
  for (int r = 0; r < 4; r++) hn[r] = nrm[w * 16 + rg * 4 + r];
  float bm = -3.4e38f;
  #pragma unroll
  for (int hh = 0; hh < 2; hh++) {
    f32x4 acc[8];
    #pragma unroll
    for (int c = 0; c < 8; c++) acc[c] = (f32x4){0.f, 0.f, 0.f, 0.f};
    #pragma unroll
    for (int ks = 0; ks < 2; ks++)
      #pragma unroll
      for (int c = 0; c < 8; c++) {
        half8 b = *(const half8*)&Wl[((hh * 8 + c) * 16 + lc) * 72 + ks * 32 + koff];
        acc[c] = mfma16(akf[ks], b, acc[c]);
      }
    #pragma unroll
    for (int c = 0; c < 8; c++)
      #pragma unroll
      for (int r = 0; r < 4; r++) bm = fmaxf(bm, acc[c][r] - hn[r]);
  }
  #pragma unroll
  for (int off = 1; off < 64; off <<= 1) bm = fmaxf(bm, __shfl_xor(bm, off, 64));
  if (lane == 0) red[w] = bm;
  __syncthreads();
  if (tid == 0)
    atomicMax(kmax, enc_f(fmaxf(fmaxf(red[0], red[1]), fmaxf(red[2], red[3]))));
}

// ============================================================================
// k_state: fused phi_k projection + chunk partial state (unchanged from R3).
// ============================================================================
__global__ __launch_bounds__(256, 2) void k_state(
    const float* __restrict__ kx, const float* __restrict__ v,
    const float* __restrict__ omega, const uint_t* __restrict__ kmax,
    half_t* __restrict__ spA)
{
  __shared__ half_t WP[256 * 72];   // omega; aliased by pkT[128][144]
  __shared__ half_t vt[80 * 136];   // [d'][j]; row64=ones
  __shared__ float nrmK[128];

  const int tid = threadIdx.x;
  const int lane = tid & 63;
  const int w = tid >> 6;
  const int lc = lane & 15, rg = lane >> 4, koff = rg * 8;
  const int wr = w * 32;
  const int blk = blockIdx.x;
  const size_t nbase = (size_t)(blk >> 5) * NSEQ + (size_t)(blk & 31) * CHUNK;
  const float gmaxv = dec_f(*kmax);

  for (int l = tid; l < 4096; l += 256) {
    int m = l >> 4, d4 = (l & 15) * 4;
    float4 o = *(const float4*)(omega + m * 64 + d4);
    half_t* p = &WP[m * 72 + d4];
    p[0] = (half_t)o.x; p[1] = (half_t)o.y; p[2] = (half_t)o.z; p[3] = (half_t)o.w;
  }
  for (int l = tid; l < 2048; l += 256) {
    int j = l >> 4, dq = (l & 15) * 4;
    float4 vv = *(const float4*)(v + (nbase + j) * 64 + dq);
    vt[(dq + 0) * 136 + j] = (half_t)vv.x;
    vt[(dq + 1) * 136 + j] = (half_t)vv.y;
    vt[(dq + 2) * 136 + j] = (half_t)vv.z;
    vt[(dq + 3) * 136 + j] = (half_t)vv.w;
  }
  if (tid < 128) vt[64 * 136 + tid] = (half_t)1.0f;

  half8 ak[2][2];
  float pn[2] = {0.f, 0.f};
  #pragma unroll
  for (int rt = 0; rt < 2; rt++) {
    const float* kp = kx + (nbase + wr + rt * 16 + lc) * 64 + koff;
    #pragma unroll
    for (int ks = 0; ks < 2; ks++) {
      float4 a = *(const float4*)(kp + ks * 32);
      float4 b = *(const float4*)(kp + ks * 32 + 4);
      a.x *= SCALE; a.y *= SCALE; a.z *= SCALE; a.w *= SCALE;
      b.x *= SCALE; b.y *= SCALE; b.z *= SCALE; b.w *= SCALE;
      pn[rt] += a.x * a.x + a.y * a.y + a.z * a.z + a.w * a.w
              + b.x * b.x + b.y * b.y + b.z * b.z + b.w * b.w;
      ak[rt][ks] = cvt_h8(a, b);
    }
    pn[rt] += __shfl_xor(pn[rt], 16, 64);
    pn[rt] += __shfl_xor(pn[rt], 32, 64);
  }
  if (rg == 0) {
    nrmK[wr + lc] = 0.5f * pn[0];
    nrmK[wr + 16 + lc] = 0.5f * pn[1];
  }
  __syncthreads();

  f32x4 accP[2][16];
  #pragma unroll
  for (int rt = 0; rt < 2; rt++)
    #pragma unroll
    for (int ct = 0; ct < 16; ct++) accP[rt][ct] = (f32x4){0.f, 0.f, 0.f, 0.f};
  #pragma unroll
  for (int ks = 0; ks < 2; ks++)
    #pragma unroll
    for (int ct = 0; ct < 16; ct++) {
      half8 b = *(const half8*)&WP[(ct * 16 + lc) * 72 + ks * 32 + koff];
      accP[0][ct] = mfma16(ak[0][ks], b, accP[0][ct]);
      accP[1][ct] = mfma16(ak[1][ks], b, accP[1][ct]);
    }
  float hnr[2][4];
  #pragma unroll
  for (int rt = 0; rt < 2; rt++)
    #pragma unroll
    for (int r = 0; r < 4; r++) hnr[rt][r] = nrmK[wr + rt * 16 + rg * 4 + r];
  #pragma unroll
  for (int rt = 0; rt < 2; rt++)
    #pragma unroll
    for (int ct = 0; ct < 16; ct++)
      #pragma unroll
      for (int r = 0; r < 4; r++)
        accP[rt][ct][r] = __expf(accP[rt][ct][r] - hnr[rt][r] - gmaxv) * 0.0625f + 1e-4f;

  half_t* pkT = WP;  // [128][144]
  #pragma unroll
  for (int h = 0; h < 2; h++) {
    __syncthreads();
    #pragma unroll
    for (int rt = 0; rt < 2; rt++)
      #pragma unroll
      for (int c8 = 0; c8 < 8; c8++) {
        int ct = h * 8 + c8;
        #pragma unroll
        for (int r = 0; r < 4; r++)
          pkT[(c8 * 16 + lc) * 144 + wr + rt * 16 + rg * 4 + r] = (half_t)accP[rt][ct][r];
      }
    __syncthreads();
    f32x4 acc2[5][2];
    #pragma unroll
    for (int rt = 0; rt < 5; rt++) {
      acc2[rt][0] = (f32x4){0.f, 0.f, 0.f, 0.f};
      acc2[rt][1] = (f32x4){0.f, 0.f, 0.f, 0.f};
    }
    #pragma unroll
    for (int ks = 0; ks < 4; ks++) {
      half8 b0 = *(const half8*)&pkT[((2 * w + 0) * 16 + lc) * 144 + ks * 32 + koff];
      half8 b1 = *(const half8*)&pkT[((2 * w + 1) * 16 + lc) * 144 + ks * 32 + koff];
      #pragma unroll
      for (int rt = 0; rt < 5; rt++) {
        half8 a = *(const half8*)&vt[(rt * 16 + lc) * 136 + ks * 32 + koff];
        acc2[rt][0] = mfma16(a, b0, acc2[rt][0]);
        acc2[rt][1] = mfma16(a, b1, acc2[rt][1]);
      }
    }
    #pragma unroll
    for (int rt = 0; rt < 5; rt++)
      #pragma unroll
      for (int c2 = 0; c2 < 2; c2++)
        #pragma unroll
        for (int r = 0; r < 4; r++) {
          int row = rt * 16 + rg * 4 + r;
          if (row < SROW)
            spA[(size_t)blk * SPITCH + row * 256 + h * 128 + (2 * w + c2) * 16 + lc] =
                (half_t)acc2[rt][c2][r];
        }
  }
}

// ============================================================================
// k_prefix: exclusive prefix over 32 chunks, f16->f16, fp32 accum (unchanged).
// ============================================================================
__global__ __launch_bounds__(256) void k_prefix(
    const uint_t* __restrict__ spA, uint_t* __restrict__ spB)
{
  int r = blockIdx.x * 256 + threadIdx.x;
  if (r >= SPITCH / 2) return;
  int bh = blockIdx.y;
  const uint_t* src = spA + (size_t)bh * NCH * (SPITCH / 2) + r;
  uint_t* dst = spB + (size_t)bh * NCH * (SPITCH / 2) + r;
  float r0 = 0.f, r1 = 0.f;
  for (int c = 0; c < NCH; c++) {
    union { uint_t u; half_t h[2]; } cv, ov;
    cv.u = src[(size_t)c * (SPITCH / 2)];
    ov.h[0] = (half_t)r0; ov.h[1] = (half_t)r1;
    dst[(size_t)c * (SPITCH / 2)] = ov.u;
    r0 += (float)cv.h[0];
    r1 += (float)cv.h[1];
  }
}

// ============================================================================
// k_attn3: fused proj + QK^T + Q@Stilde + masked A@v + divide.
// - omega double-buffered in REGISTERS (prefetched during MFMA phase)
// - SST / v prefetched to regs during MFMA phase (T14 issue-early)
// - all LDS MFMA tiles XOR-swizzled (T2), unpadded -> 43.5 KB -> 3 blocks/CU
// - coalesced out stores via LDS staging
// sm halfs: PQ[0,8192) PK[8192,16384) SST[16384,21504)
// phase2:   AS = sm+0 [128][64], VT = sm+8192 [80][128]
// epilogue: OS = (float*)sm [128][68]
// ============================================================================
__global__ __launch_bounds__(256, 3) void k_attn3(
    const float* __restrict__ q, const float* __restrict__ kx,
    const float* __restrict__ v, const float* __restrict__ omega,
    const float* __restrict__ rowmQ, const uint_t* __restrict__ kmax,
    const half_t* __restrict__ spB, float* __restrict__ out)
{
  __shared__ half_t sm[21504];
  __shared__ float nrmK[128];
  half_t* PQ  = sm;
  half_t* PK  = sm + 8192;
  half_t* SST = sm + 16384;
  half_t* AS  = sm;
  half_t* VT  = sm + 8192;

  const int tid = threadIdx.x;
  const int lane = tid & 63;
  const int w = tid >> 6;
  const int lc = lane & 15, rg = lane >> 4, koff = rg * 8;
  const int wr = w * 32;
  const int blk = blockIdx.x;
  const size_t nbase = (size_t)(blk >> 5) * NSEQ + (size_t)(blk & 31) * CHUNK;
  const half_t* spb = spB + (size_t)blk * SPITCH;
  const float gmaxv = dec_f(*kmax);
  const int swz = (lc & 7) << 3;

  // ---- prologue ----
  float rowm[2][4];
  #pragma unroll
  for (int rt = 0; rt < 2; rt++)
    #pragma unroll
    for (int r = 0; r < 4; r++)
      rowm[rt][r] = rowmQ[nbase + wr + rt * 16 + rg * 4 + r];

  half8 aq[2][2], ak[2][2];
  float pn[2] = {0.f, 0.f};
  #pragma unroll
  for (int rt = 0; rt < 2; rt++) {
    const float* qp = q + (nbase + wr + rt * 16 + lc) * 64 + koff;
    const float* kp = kx + (nbase + wr + rt * 16 + lc) * 64 + koff;
    #pragma unroll
    for (int ks = 0; ks < 2; ks++) {
      float4 a = *(const float4*)(qp + ks * 32);
      float4 b = *(const float4*)(qp + ks * 32 + 4);
      a.x *= SCALE; a.y *= SCALE; a.z *= SCALE; a.w *= SCALE;
      b.x *= SCALE; b.y *= SCALE; b.z *= SCALE; b.w *= SCALE;
      aq[rt][ks] = cvt_h8(a, b);
      float4 c = *(const float4*)(kp + ks * 32);
      float4 d = *(const float4*)(kp + ks * 32 + 4);
      c.x *= SCALE; c.y *= SCALE; c.z *= SCALE; c.w *= SCALE;
      d.x *= SCALE; d.y *= SCALE; d.z *= SCALE; d.w *= SCALE;
      pn[rt] += c.x * c.x + c.y * c.y + c.z * c.z + c.w * c.w
              + d.x * d.x + d.y * d.y + d.z * d.z + d.w * d.w;
      ak[rt][ks] = cvt_h8(c, d);
    }
    pn[rt] += __shfl_xor(pn[rt], 16, 64);
    pn[rt] += __shfl_xor(pn[rt], 32, 64);
  }
  if (rg == 0) {
    nrmK[wr + lc] = 0.5f * pn[0];
    nrmK[wr + 16 + lc] = 0.5f * pn[1];
  }

  half8 bw0[4][2], bw1[4][2];
  half8 sstA, sstB, sstC = half8{};

#define LOADW(BW, MT) do {                                                    \
    _Pragma("unroll") for (int ct = 0; ct < 4; ct++) {                        \
      const float* op = omega + ((MT) * 64 + ct * 16 + lc) * 64 + koff;       \
      float4 a0_ = *(const float4*)(op);                                      \
      float4 b0_ = *(const float4*)(op + 4);                                  \
      float4 a1_ = *(const float4*)(op + 32);                                 \
      float4 b1_ = *(const float4*)(op + 36);                                 \
      BW[ct][0] = cvt_h8(a0_, b0_);                                          \
      BW[ct][1] = cvt_h8(a1_, b1_);                                          \
    } } while (0)

#define LOADSST(MT) do {                                                      \
    { int l = tid;       int ro = l >> 3, c8 = (l & 7) * 8;                   \
      sstA = *(const half8*)(spb + ro * 256 + (MT) * 64 + c8); }              \
    { int l = tid + 256; int ro = l >> 3, c8 = (l & 7) * 8;                   \
      sstB = *(const half8*)(spb + ro * 256 + (MT) * 64 + c8); }              \
    if (tid < 8) { int l = tid + 512; int ro = l >> 3, c8 = (l & 7) * 8;      \
      sstC = *(const half8*)(spb + ro * 256 + (MT) * 64 + c8); }              \
  } while (0)

#define STAGEPHASE(BW) do {                                                   \
    { int l = tid;       int ro = l >> 3, c8 = (l & 7) * 8;                   \
      *(half8*)&SST[ro * 64 + (c8 ^ ((ro & 7) << 3))] = sstA; }               \
    { int l = tid + 256; int ro = l >> 3, c8 = (l & 7) * 8;                   \
      *(half8*)&SST[ro * 64 + (c8 ^ ((ro & 7) << 3))] = sstB; }               \
    if (tid < 8) { int l = tid + 512; int ro = l >> 3, c8 = (l & 7) * 8;      \
      *(half8*)&SST[ro * 64 + (c8 ^ ((ro & 7) << 3))] = sstC; }               \
    f32x4 accP[2][4];                                                         \
    _Pragma("unroll") for (int rt = 0; rt < 2; rt++)                          \
      _Pragma("unroll") for (int ct = 0; ct < 4; ct++)                        \
        accP[rt][ct] = (f32x4){0.f, 0.f, 0.f, 0.f};                           \
    _Pragma("unroll") for (int ks = 0; ks < 2; ks++)                          \
      _Pragma("unroll") for (int ct = 0; ct < 4; ct++) {                      \
        accP[0][ct] = mfma16(aq[0][ks], BW[ct][ks], accP[0][ct]);             \
        accP[1][ct] = mfma16(aq[1][ks], BW[ct][ks], accP[1][ct]);             \
      }                                                                       \
    _Pragma("unroll") for (int rt = 0; rt < 2; rt++)                          \
      _Pragma("unroll") for (int ct = 0; ct < 4; ct++)                        \
        _Pragma("unroll") for (int r = 0; r < 4; r++) {                       \
          int i = wr + rt * 16 + rg * 4 + r;                                  \
          float val = __expf(accP[rt][ct][r] - rowm[rt][r]) * 0.0625f + 1e-4f;\
          PQ[i * 64 + ((ct * 16 + lc) ^ ((i & 7) << 3))] = (half_t)val;       \
        }                                                                     \
    _Pragma("unroll") for (int rt = 0; rt < 2; rt++)                          \
      _Pragma("unroll") for (int ct = 0; ct < 4; ct++)                        \
        accP[rt][ct] = (f32x4){0.f, 0.f, 0.f, 0.f};                           \
    _Pragma("unroll") for (int ks = 0; ks < 2; ks++)                          \
      _Pragma("unroll") for (int ct = 0; ct < 4; ct++) {                      \
        accP[0][ct] = mfma16(ak[0][ks], BW[ct][ks], accP[0][ct]);             \
        accP[1][ct] = mfma16(ak[1][ks], BW[ct][ks], accP[1][ct]);             \
      }                                                                       \
    _Pragma("unroll") for (int rt = 0; rt < 2; rt++)                          \
      _Pragma("unroll") for (int ct = 0; ct < 4; ct++)                        \
        _Pragma("unroll") for (int r = 0; r < 4; r++) {                       \
          int i = wr + rt * 16 + rg * 4 + r;                                  \
          float val = __expf(accP[rt][ct][r] - hnr[rt][r] - gmaxv) * 0.0625f + 1e-4f; \
          PK[i * 64 + ((ct * 16 + lc) ^ ((i & 7) << 3))] = (half_t)val;       \
        }                                                                     \
  } while (0)

#define COMPUTEPHASE() do {                                                   \
    _Pragma("unroll") for (int ks2 = 0; ks2 < 64; ks2 += 32) {                \
      int sA = (ks2 + koff) ^ swz;                                            \
      half8 a0 = *(const half8*)&PQ[(wr + lc) * 64 + sA];                     \
      half8 a1 = *(const half8*)&PQ[(wr + 16 + lc) * 64 + sA];                \
      _Pragma("unroll") for (int ct = 0; ct < 8; ct++) {                      \
        half8 b = *(const half8*)&PK[(ct * 16 + lc) * 64 + sA];               \
        accA[0][ct] = mfma16(a0, b, accA[0][ct]);                             \
        accA[1][ct] = mfma16(a1, b, accA[1][ct]);                             \
      }                                                                       \
      _Pragma("unroll") for (int cs = 0; cs < 5; cs++) {                      \
        half8 b = *(const half8*)&SST[(cs * 16 + lc) * 64 + sA];              \
        accO[0][cs] = mfma16(a0, b, accO[0][cs]);                             \
        accO[1][cs] = mfma16(a1, b, accO[1][cs]);                             \
      }                                                                       \
    } } while (0)

  LOADW(bw0, 0);
  LOADSST(0);
  __syncthreads();   // nrmK visible
  float hnr[2][4];
  #pragma unroll
  for (int rt = 0; rt < 2; rt++)
    #pragma unroll
    for (int r = 0; r < 4; r++) hnr[rt][r] = nrmK[wr + rt * 16 + rg * 4 + r];

  f32x4 accA[2][8], accO[2][5];
  #pragma unroll
  for (int rt = 0; rt < 2; rt++) {
    #pragma unroll
    for (int ct = 0; ct < 8; ct++) accA[rt][ct] = (f32x4){0.f, 0.f, 0.f, 0.f};
    #pragma unroll
    for (int cs = 0; cs < 5; cs++) accO[rt][cs] = (f32x4){0.f, 0.f, 0.f, 0.f};
  }

  float4 vv0, vv1, vv2, vv3, vv4, vv5, vv6, vv7;

  // mt = 0
  STAGEPHASE(bw0);
  __syncthreads();
  LOADW(bw1, 1); LOADSST(1);
  COMPUTEPHASE();
  __syncthreads();
  // mt = 1
  STAGEPHASE(bw1);
  __syncthreads();
  LOADW(bw0, 2); LOADSST(2);
  COMPUTEPHASE();
  __syncthreads();
  // mt = 2
  STAGEPHASE(bw0);
  __syncthreads();
  LOADW(bw1, 3); LOADSST(3);
  COMPUTEPHASE();
  __syncthreads();
  // mt = 3
  STAGEPHASE(bw1);
  __syncthreads();
  {  // prefetch v during last compute phase
    const float* vb = v + nbase * 64;
    vv0 = *(const float4*)(vb + ((tid + 0 * 256) >> 4) * 64 + ((tid + 0 * 256) & 15) * 4);
    vv1 = *(const float4*)(vb + ((tid + 1 * 256) >> 4) * 64 + ((tid + 1 * 256) & 15) * 4);
    vv2 = *(const float4*)(vb + ((tid + 2 * 256) >> 4) * 64 + ((tid + 2 * 256) & 15) * 4);
    vv3 = *(const float4*)(vb + ((tid + 3 * 256) >> 4) * 64 + ((tid + 3 * 256) & 15) * 4);
    vv4 = *(const float4*)(vb + ((tid + 4 * 256) >> 4) * 64 + ((tid + 4 * 256) & 15) * 4);
    vv5 = *(const float4*)(vb + ((tid + 5 * 256) >> 4) * 64 + ((tid + 5 * 256) & 15) * 4);
    vv6 = *(const float4*)(vb + ((tid + 6 * 256) >> 4) * 64 + ((tid + 6 * 256) & 15) * 4);
    vv7 = *(const float4*)(vb + ((tid + 7 * 256) >> 4) * 64 + ((tid + 7 * 256) & 15) * 4);
  }
  COMPUTEPHASE();
  __syncthreads();

  // ---- phase 2: VT staging (swizzled) + masked A @ v_aug ----
#define PUTV(VV, E) do {                                                      \
    int l = tid + (E) * 256; int j = l >> 4, dq = (l & 15) * 4;               \
    VT[(dq + 0) * 128 + (j ^ (((dq + 0) & 7) << 3))] = (half_t)VV.x;          \
    VT[(dq + 1) * 128 + (j ^ (((dq + 1) & 7) << 3))] = (half_t)VV.y;          \
    VT[(dq + 2) * 128 + (j ^ (((dq + 2) & 7) << 3))] = (half_t)VV.z;          \
    VT[(dq + 3) * 128 + (j ^ (((dq + 3) & 7) << 3))] = (half_t)VV.w;          \
  } while (0)
  PUTV(vv0, 0); PUTV(vv1, 1); PUTV(vv2, 2); PUTV(vv3, 3);
  PUTV(vv4, 4); PUTV(vv5, 5); PUTV(vv6, 6); PUTV(vv7, 7);
  if (tid < 128) VT[64 * 128 + tid] = (half_t)1.0f;   // row 64: (64&7)=0, no swz

  #pragma unroll
  for (int h = 0; h < 2; h++) {
    #pragma unroll
    for (int rt = 0; rt < 2; rt++)
      #pragma unroll
      for (int c4 = 0; c4 < 4; c4++) {
        int ct = h * 4 + c4;
        int j = ct * 16 + lc;
        #pragma unroll
        for (int r = 0; r < 4; r++) {
          int i = wr + rt * 16 + rg * 4 + r;
          float val = (j <= i) ? accA[rt][ct][r] : 0.f;
          AS[i * 64 + ((j - h * 64) ^ ((i & 7) << 3))] = (half_t)val;
        }
      }
    if (h == 0) __syncthreads();   // VT staged by all threads
    #pragma unroll
    for (int ks2 = 0; ks2 < 64; ks2 += 32) {
      int sA = (ks2 + koff) ^ swz;
      int sV = (h * 64 + ks2 + koff) ^ swz;
      half8 a0 = *(const half8*)&AS[(wr + lc) * 64 + sA];
      half8 a1 = *(const half8*)&AS[(wr + 16 + lc) * 64 + sA];
      #pragma unroll
      for (int cs = 0; cs < 5; cs++) {
        half8 b = *(const half8*)&VT[(cs * 16 + lc) * 128 + sV];
        accO[0][cs] = mfma16(a0, b, accO[0][cs]);
        accO[1][cs] = mfma16(a1, b, accO[1][cs]);
      }
    }
  }

  // ---- epilogue: divide by den, stage to LDS f32, coalesced store ----
  __syncthreads();   // all AV MFMA reads of AS/VT done
  float* OS = (float*)sm;   // [128][68]
  #pragma unroll
  for (int rt = 0; rt < 2; rt++)
    #pragma unroll
    for (int r = 0; r < 4; r++) {
      float den = __shfl(accO[rt][4][r], (lane & 48), 64) + 1e-6f;
      float inv = 1.0f / den;
      int i = wr + rt * 16 + rg * 4 + r;
      #pragma unroll
      for (int cs = 0; cs < 4; cs++)
        OS[i * 68 + cs * 16 + lc] = accO[rt][cs][r] * inv;
    }
  __syncthreads();
  #pragma unroll
  for (int e = 0; e < 8; e++) {
    int l = tid + e * 256;            // 2048 float4s
    int row = l >> 4, c4 = (l & 15) * 4;
    float4 t4 = *(const float4*)&OS[row * 68 + c4];
    *(float4*)(out + (nbase + row) * 64 + c4) = t4;
  }
#undef LOADW
#undef LOADSST
#undef STAGEPHASE
#undef COMPUTEPHASE
#undef PUTV
}

// ============================================================================
// launcher
// ws: rowmQ f32 @0 (512KB) | spA f16 @524288 (33.3MB) | spB f16 @34603008
//     (33.3MB) | kmax u32 @68681728   -> ~68.7 MB total
// ============================================================================
extern "C" void kernel_launch(void* const* d_in, const int* in_sizes, int n_in,
                              void* d_out, int out_size, void* d_ws, size_t ws_size,
                              hipStream_t stream) {
  const float* q = (const float*)d_in[0];
  const float* k = (const float*)d_in[1];
  const float* v = (const float*)d_in[2];
  const float* omega = (const float*)d_in[3];
  float* out = (float*)d_out;
  char* ws = (char*)d_ws;

  float*  rowmQ = (float*)(ws + 0);
  half_t* spA   = (half_t*)(ws + 524288);
  half_t* spB   = (half_t*)(ws + 34603008);
  uint_t* kmax  = (uint_t*)(ws + 68681728);

  k_init<<<1, 1, 0, stream>>>(kmax);
  k_maxes<<<2048, 256, 0, stream>>>(q, k, omega, rowmQ, kmax);
  k_state<<<1024, 256, 0, stream>>>(k, v, omega, kmax, spA);
  k_prefix<<<dim3(33, 32), 256, 0, stream>>>((const uint_t*)spA, (uint_t*)spB);
  k_attn3<<<1024, 256, 0, stream>>>(q, k, v, omega, rowmQ, kmax, spB, out);
}

// Round 5
// 151.593 us; speedup vs baseline: 2.5677x; 2.5677x over previous
//
#include <hip/hip_runtime.h>
#include <cstddef>

// B=2,H=16 -> BH=32
#define BH    32
#define NSEQ  4096
#define MFEAT 256
#define CHUNK 128
#define NCH   32
#define SROW  65          // 64 d-rows + 1 z-row
#define SPITCH (SROW*256) // 16640 f16 per (bh,chunk) state

#define SCALE 0.35355339059327373f  // 64^-0.25

typedef unsigned int uint_t;
typedef _Float16 half_t;
typedef __attribute__((ext_vector_type(8))) _Float16 half8;
typedef __attribute__((ext_vector_type(4))) float f32x4;

__device__ __forceinline__ f32x4 mfma16(half8 a, half8 b, f32x4 c) {
  return __builtin_amdgcn_mfma_f32_16x16x32_f16(a, b, c, 0, 0, 0);
}
__device__ __forceinline__ uint_t enc_f(float x) {
  uint_t u = __float_as_uint(x);
  return (u & 0x80000000u) ? ~u : (u | 0x80000000u);
}
__device__ __forceinline__ float dec_f(uint_t u) {
  u = (u & 0x80000000u) ? (u ^ 0x80000000u) : ~u;
  return __uint_as_float(u);
}
__device__ __forceinline__ half8 cvt_h8(float4 a, float4 b) {
  half8 h;
  h[0] = (half_t)a.x; h[1] = (half_t)a.y; h[2] = (half_t)a.z; h[3] = (half_t)a.w;
  h[4] = (half_t)b.x; h[5] = (half_t)b.y; h[6] = (half_t)b.z; h[7] = (half_t)b.w;
  return h;
}

__global__ void k_init(uint_t* kmax) { *kmax = enc_f(-__builtin_inff()); }

// ============================================================================
// k_maxes: 64 rows of q AND k per block, reg a-frags, omega in LDS, 1 barrier.
//   q: rowmQ[row] = max_m (q_s @ w^T)   (norm cancels in per-row max)
//   k: atomicMax(kmax, max(proj - 0.5|x|^2))
// LDS 37 KB -> 4 blocks/CU. VGPR demand modest -> no spill at (256,4).
// ============================================================================
__global__ __launch_bounds__(256, 4) void k_maxes(
    const float* __restrict__ q, const float* __restrict__ kx,
    const float* __restrict__ omega, float* __restrict__ rowmQ,
    uint_t* __restrict__ kmax)
{
  __shared__ half_t Wl[256 * 72];
  __shared__ float nrm[64];
  __shared__ float red[4];

  const int tid = threadIdx.x;
  const int lane = tid & 63;
  const int w = tid >> 6;
  const int lc = lane & 15, rg = lane >> 4, koff = rg * 8;
  const size_t rowbase = (size_t)blockIdx.x * 64;

  // omega fp32 -> f16 LDS
  for (int l = tid; l < 4096; l += 256) {
    int m = l >> 4, d4 = (l & 15) * 4;
    float4 o = *(const float4*)(omega + m * 64 + d4);
    half_t* p = &Wl[m * 72 + d4];
    p[0] = (half_t)o.x; p[1] = (half_t)o.y; p[2] = (half_t)o.z; p[3] = (half_t)o.w;
  }
  // q,k a-frags direct to regs; k row norms via shfl
  half8 aq[2], akf[2];
  {
    const float* qp = q + (rowbase + w * 16 + lc) * 64 + koff;
    const float* kp = kx + (rowbase + w * 16 + lc) * 64 + koff;
    float pn = 0.f;
    #pragma unroll
    for (int ks = 0; ks < 2; ks++) {
      float4 a = *(const float4*)(qp + ks * 32);
      float4 b = *(const float4*)(qp + ks * 32 + 4);
      a.x *= SCALE; a.y *= SCALE; a.z *= SCALE; a.w *= SCALE;
      b.x *= SCALE; b.y *= SCALE; b.z *= SCALE; b.w *= SCALE;
      aq[ks] = cvt_h8(a, b);
      float4 c = *(const float4*)(kp + ks * 32);
      float4 d = *(const float4*)(kp + ks * 32 + 4);
      c.x *= SCALE; c.y *= SCALE; c.z *= SCALE; c.w *= SCALE;
      d.x *= SCALE; d.y *= SCALE; d.z *= SCALE; d.w *= SCALE;
      pn += c.x * c.x + c.y * c.y + c.z * c.z + c.w * c.w
          + d.x * d.x + d.y * d.y + d.z * d.z + d.w * d.w;
      akf[ks] = cvt_h8(c, d);
    }
    pn += __shfl_xor(pn, 16, 64);
    pn += __shfl_xor(pn, 32, 64);
    if (rg == 0) nrm[w * 16 + lc] = 0.5f * pn;
  }
  __syncthreads();

  // proj q in two 8-ct chunks -> per-row max
  float mrow[4] = {-3.4e38f, -3.4e38f, -3.4e38f, -3.4e38f};
  #pragma unroll
  for (int hh = 0; hh < 2; hh++) {
    f32x4 acc[8];
    #pragma unroll
    for (int c = 0; c < 8; c++) acc[c] = (f32x4){0.f, 0.f, 0.f, 0.f};
    #pragma unroll
    for (int ks = 0; ks < 2; ks++)
      #pragma unroll
      for (int c = 0; c < 8; c++) {
        half8 b = *(const half8*)&Wl[((hh * 8 + c) * 16 + lc) * 72 + ks * 32 + koff];
        acc[c] = mfma16(aq[ks], b, acc[c]);
      }
    #pragma unroll
    for (int c = 0; c < 8; c++)
      #pragma unroll
      for (int r = 0; r < 4; r++) mrow[r] = fmaxf(mrow[r], acc[c][r]);
  }
  #pragma unroll
  for (int r = 0; r < 4; r++) {
    float m0 = mrow[r];
    m0 = fmaxf(m0, __shfl_xor(m0, 1, 64));
    m0 = fmaxf(m0, __shfl_xor(m0, 2, 64));
    m0 = fmaxf(m0, __shfl_xor(m0, 4, 64));
    m0 = fmaxf(m0, __shfl_xor(m0, 8, 64));
    if (lc == 0) rowmQ[rowbase + w * 16 + rg * 4 + r] = m0;
  }

  // proj k -> global max
  float hn[4];
  #pragma unroll
  for (int r = 0; r < 4; r++) hn[r] = nrm[w * 16 + rg * 4 + r];
  float bm = -3.4e38f;
  #pragma unroll
  for (int hh = 0; hh < 2; hh++) {
    f32x4 acc[8];
    #pragma unroll
    for (int c = 0; c < 8; c++) acc[c] = (f32x4){0.f, 0.f, 0.f, 0.f};
    #pragma unroll
    for (int ks = 0; ks < 2; ks++)
      #pragma unroll
      for (int c = 0; c < 8; c++) {
        half8 b = *(const half8*)&Wl[((hh * 8 + c) * 16 + lc) * 72 + ks * 32 + koff];
        acc[c] = mfma16(akf[ks], b, acc[c]);
      }
    #pragma unroll
    for (int c = 0; c < 8; c++)
      #pragma unroll
      for (int r = 0; r < 4; r++) bm = fmaxf(bm, acc[c][r] - hn[r]);
  }
  #pragma unroll
  for (int off = 1; off < 64; off <<= 1) bm = fmaxf(bm, __shfl_xor(bm, off, 64));
  if (lane == 0) red[w] = bm;
  __syncthreads();
  if (tid == 0)
    atomicMax(kmax, enc_f(fmaxf(fmaxf(red[0], red[1]), fmaxf(red[2], red[3]))));
}

// ============================================================================
// k_state: fused phi_k projection + chunk partial state (unchanged from R3).
// ============================================================================
__global__ __launch_bounds__(256, 2) void k_state(
    const float* __restrict__ kx, const float* __restrict__ v,
    const float* __restrict__ omega, const uint_t* __restrict__ kmax,
    half_t* __restrict__ spA)
{
  __shared__ half_t WP[256 * 72];   // omega; aliased by pkT[128][144]
  __shared__ half_t vt[80 * 136];   // [d'][j]; row64=ones
  __shared__ float nrmK[128];

  const int tid = threadIdx.x;
  const int lane = tid & 63;
  const int w = tid >> 6;
  const int lc = lane & 15, rg = lane >> 4, koff = rg * 8;
  const int wr = w * 32;
  const int blk = blockIdx.x;
  const size_t nbase = (size_t)(blk >> 5) * NSEQ + (size_t)(blk & 31) * CHUNK;
  const float gmaxv = dec_f(*kmax);

  for (int l = tid; l < 4096; l += 256) {
    int m = l >> 4, d4 = (l & 15) * 4;
    float4 o = *(const float4*)(omega + m * 64 + d4);
    half_t* p = &WP[m * 72 + d4];
    p[0] = (half_t)o.x; p[1] = (half_t)o.y; p[2] = (half_t)o.z; p[3] = (half_t)o.w;
  }
  for (int l = tid; l < 2048; l += 256) {
    int j = l >> 4, dq = (l & 15) * 4;
    float4 vv = *(const float4*)(v + (nbase + j) * 64 + dq);
    vt[(dq + 0) * 136 + j] = (half_t)vv.x;
    vt[(dq + 1) * 136 + j] = (half_t)vv.y;
    vt[(dq + 2) * 136 + j] = (half_t)vv.z;
    vt[(dq + 3) * 136 + j] = (half_t)vv.w;
  }
  if (tid < 128) vt[64 * 136 + tid] = (half_t)1.0f;

  half8 ak[2][2];
  float pn[2] = {0.f, 0.f};
  #pragma unroll
  for (int rt = 0; rt < 2; rt++) {
    const float* kp = kx + (nbase + wr + rt * 16 + lc) * 64 + koff;
    #pragma unroll
    for (int ks = 0; ks < 2; ks++) {
      float4 a = *(const float4*)(kp + ks * 32);
      float4 b = *(const float4*)(kp + ks * 32 + 4);
      a.x *= SCALE; a.y *= SCALE; a.z *= SCALE; a.w *= SCALE;
      b.x *= SCALE; b.y *= SCALE; b.z *= SCALE; b.w *= SCALE;
      pn[rt] += a.x * a.x + a.y * a.y + a.z * a.z + a.w * a.w
              + b.x * b.x + b.y * b.y + b.z * b.z + b.w * b.w;
      ak[rt][ks] = cvt_h8(a, b);
    }
    pn[rt] += __shfl_xor(pn[rt], 16, 64);
    pn[rt] += __shfl_xor(pn[rt], 32, 64);
  }
  if (rg == 0) {
    nrmK[wr + lc] = 0.5f * pn[0];
    nrmK[wr + 16 + lc] = 0.5f * pn[1];
  }
  __syncthreads();

  f32x4 accP[2][16];
  #pragma unroll
  for (int rt = 0; rt < 2; rt++)
    #pragma unroll
    for (int ct = 0; ct < 16; ct++) accP[rt][ct] = (f32x4){0.f, 0.f, 0.f, 0.f};
  #pragma unroll
  for (int ks = 0; ks < 2; ks++)
    #pragma unroll
    for (int ct = 0; ct < 16; ct++) {
      half8 b = *(const half8*)&WP[(ct * 16 + lc) * 72 + ks * 32 + koff];
      accP[0][ct] = mfma16(ak[0][ks], b, accP[0][ct]);
      accP[1][ct] = mfma16(ak[1][ks], b, accP[1][ct]);
    }
  float hnr[2][4];
  #pragma unroll
  for (int rt = 0; rt < 2; rt++)
    #pragma unroll
    for (int r = 0; r < 4; r++) hnr[rt][r] = nrmK[wr + rt * 16 + rg * 4 + r];
  #pragma unroll
  for (int rt = 0; rt < 2; rt++)
    #pragma unroll
    for (int ct = 0; ct < 16; ct++)
      #pragma unroll
      for (int r = 0; r < 4; r++)
        accP[rt][ct][r] = __expf(accP[rt][ct][r] - hnr[rt][r] - gmaxv) * 0.0625f + 1e-4f;

  half_t* pkT = WP;  // [128][144]
  #pragma unroll
  for (int h = 0; h < 2; h++) {
    __syncthreads();
    #pragma unroll
    for (int rt = 0; rt < 2; rt++)
      #pragma unroll
      for (int c8 = 0; c8 < 8; c8++) {
        int ct = h * 8 + c8;
        #pragma unroll
        for (int r = 0; r < 4; r++)
          pkT[(c8 * 16 + lc) * 144 + wr + rt * 16 + rg * 4 + r] = (half_t)accP[rt][ct][r];
      }
    __syncthreads();
    f32x4 acc2[5][2];
    #pragma unroll
    for (int rt = 0; rt < 5; rt++) {
      acc2[rt][0] = (f32x4){0.f, 0.f, 0.f, 0.f};
      acc2[rt][1] = (f32x4){0.f, 0.f, 0.f, 0.f};
    }
    #pragma unroll
    for (int ks = 0; ks < 4; ks++) {
      half8 b0 = *(const half8*)&pkT[((2 * w + 0) * 16 + lc) * 144 + ks * 32 + koff];
      half8 b1 = *(const half8*)&pkT[((2 * w + 1) * 16 + lc) * 144 + ks * 32 + koff];
      #pragma unroll
      for (int rt = 0; rt < 5; rt++) {
        half8 a = *(const half8*)&vt[(rt * 16 + lc) * 136 + ks * 32 + koff];
        acc2[rt][0] = mfma16(a, b0, acc2[rt][0]);
        acc2[rt][1] = mfma16(a, b1, acc2[rt][1]);
      }
    }
    #pragma unroll
    for (int rt = 0; rt < 5; rt++)
      #pragma unroll
      for (int c2 = 0; c2 < 2; c2++)
        #pragma unroll
        for (int r = 0; r < 4; r++) {
          int row = rt * 16 + rg * 4 + r;
          if (row < SROW)
            spA[(size_t)blk * SPITCH + row * 256 + h * 128 + (2 * w + c2) * 16 + lc] =
                (half_t)acc2[rt][c2][r];
        }
  }
}

// ============================================================================
// k_prefix: exclusive prefix over 32 chunks, f16->f16, fp32 accum (unchanged).
// ============================================================================
__global__ __launch_bounds__(256) void k_prefix(
    const uint_t* __restrict__ spA, uint_t* __restrict__ spB)
{
  int r = blockIdx.x * 256 + threadIdx.x;
  if (r >= SPITCH / 2) return;
  int bh = blockIdx.y;
  const uint_t* src = spA + (size_t)bh * NCH * (SPITCH / 2) + r;
  uint_t* dst = spB + (size_t)bh * NCH * (SPITCH / 2) + r;
  float r0 = 0.f, r1 = 0.f;
  for (int c = 0; c < NCH; c++) {
    union { uint_t u; half_t h[2]; } cv, ov;
    cv.u = src[(size_t)c * (SPITCH / 2)];
    ov.h[0] = (half_t)r0; ov.h[1] = (half_t)r1;
    dst[(size_t)c * (SPITCH / 2)] = ov.u;
    r0 += (float)cv.h[0];
    r1 += (float)cv.h[1];
  }
}

// ============================================================================
// k_attn4: fused proj + QK^T + Q@Stilde + masked A@v + divide.
// vs R4's k_attn3: omega lives in LDS (loaded ONCE, swizzled) instead of
// register double-buffering; __launch_bounds__(256,2) -> 256-VGPR cap, NO
// SPILL (R4's (256,3)=84 VGPR cap caused 900 MB of scratch HBM traffic).
// T2 XOR-swizzle on all MFMA tiles; SST/v prefetched to regs during MFMA
// phases (T14); coalesced out-store via LDS.
// LDS layout (f16 units):
//   Wl  [0,16384)      omega [256][64] swz
//   PQ  [16384,24576)  [128][64] swz     | phase2: AS aliases
//   PK  [24576,32768)  [128][64] swz     | phase2: VT [80][128] @24576..34816
//   SST [32768,37888)  [80][64] swz (rows 0..64 data, 65..79 zeroed)
//   epilogue: OS f32[128][68] aliases [0,17408)
// Total 75776 B + nrmK -> 2 blocks/CU.
// ============================================================================
__global__ __launch_bounds__(256, 2) void k_attn4(
    const float* __restrict__ q, const float* __restrict__ kx,
    const float* __restrict__ v, const float* __restrict__ omega,
    const float* __restrict__ rowmQ, const uint_t* __restrict__ kmax,
    const half_t* __restrict__ spB, float* __restrict__ out)
{
  __shared__ half_t sm[37888];
  __shared__ float nrmK[128];
  half_t* Wl  = sm;
  half_t* PQ  = sm + 16384;
  half_t* PK  = sm + 24576;
  half_t* SST = sm + 32768;
  half_t* AS  = sm + 16384;
  half_t* VT  = sm + 24576;

  const int tid = threadIdx.x;
  const int lane = tid & 63;
  const int w = tid >> 6;
  const int lc = lane & 15, rg = lane >> 4, koff = rg * 8;
  const int wr = w * 32;
  const int blk = blockIdx.x;
  const size_t nbase = (size_t)(blk >> 5) * NSEQ + (size_t)(blk & 31) * CHUNK;
  const half_t* spb = spB + (size_t)blk * SPITCH;
  const float gmaxv = dec_f(*kmax);
  const int swz = (lc & 7) << 3;

  // ---- prologue ----
  // omega fp32 -> f16 LDS, swizzled rows
  for (int l = tid; l < 2048; l += 256) {
    int m = l >> 3, d8 = (l & 7) * 8;
    float4 a = *(const float4*)(omega + m * 64 + d8);
    float4 b = *(const float4*)(omega + m * 64 + d8 + 4);
    *(half8*)&Wl[m * 64 + (d8 ^ ((m & 7) << 3))] = cvt_h8(a, b);
  }
  // zero SST pad rows 65..79 (cols feed accO[.][4] lanes lc!=0, unread; zero for safety)
  for (int l = tid; l < 480; l += 256)
    ((uint_t*)&SST[65 * 64])[l] = 0u;

  float rowm[2][4];
  #pragma unroll
  for (int rt = 0; rt < 2; rt++)
    #pragma unroll
    for (int r = 0; r < 4; r++)
      rowm[rt][r] = rowmQ[nbase + wr + rt * 16 + rg * 4 + r];

  half8 aq[2][2], ak[2][2];
  float pn[2] = {0.f, 0.f};
  #pragma unroll
  for (int rt = 0; rt < 2; rt++) {
    const float* qp = q + (nbase + wr + rt * 16 + lc) * 64 + koff;
    const float* kp = kx + (nbase + wr + rt * 16 + lc) * 64 + koff;
    #pragma unroll
    for (int ks = 0; ks < 2; ks++) {
      float4 a = *(const float4*)(qp + ks * 32);
      float4 b = *(const float4*)(qp + ks * 32 + 4);
      a.x *= SCALE; a.y *= SCALE; a.z *= SCALE; a.w *= SCALE;
      b.x *= SCALE; b.y *= SCALE; b.z *= SCALE; b.w *= SCALE;
      aq[rt][ks] = cvt_h8(a, b);
      float4 c = *(const float4*)(kp + ks * 32);
      float4 d = *(const float4*)(kp + ks * 32 + 4);
      c.x *= SCALE; c.y *= SCALE; c.z *= SCALE; c.w *= SCALE;
      d.x *= SCALE; d.y *= SCALE; d.z *= SCALE; d.w *= SCALE;
      pn[rt] += c.x * c.x + c.y * c.y + c.z * c.z + c.w * c.w
              + d.x * d.x + d.y * d.y + d.z * d.z + d.w * d.w;
      ak[rt][ks] = cvt_h8(c, d);
    }
    pn[rt] += __shfl_xor(pn[rt], 16, 64);
    pn[rt] += __shfl_xor(pn[rt], 32, 64);
  }
  if (rg == 0) {
    nrmK[wr + lc] = 0.5f * pn[0];
    nrmK[wr + 16 + lc] = 0.5f * pn[1];
  }

  half8 sstA, sstB, sstC = half8{};

#define LOADSST(MT) do {                                                      \
    { int l = tid;       int ro = l >> 3, c8 = (l & 7) * 8;                   \
      sstA = *(const half8*)(spb + ro * 256 + (MT) * 64 + c8); }              \
    { int l = tid + 256; int ro = l >> 3, c8 = (l & 7) * 8;                   \
      sstB = *(const half8*)(spb + ro * 256 + (MT) * 64 + c8); }              \
    if (tid < 8) { int l = tid + 512; int ro = l >> 3, c8 = (l & 7) * 8;      \
      sstC = *(const half8*)(spb + ro * 256 + (MT) * 64 + c8); }              \
  } while (0)

#define STAGEPHASE(MT) do {                                                   \
    { int l = tid;       int ro = l >> 3, c8 = (l & 7) * 8;                   \
      *(half8*)&SST[ro * 64 + (c8 ^ ((ro & 7) << 3))] = sstA; }               \
    { int l = tid + 256; int ro = l >> 3, c8 = (l & 7) * 8;                   \
      *(half8*)&SST[ro * 64 + (c8 ^ ((ro & 7) << 3))] = sstB; }               \
    if (tid < 8) { int l = tid + 512; int ro = l >> 3, c8 = (l & 7) * 8;      \
      *(half8*)&SST[ro * 64 + (c8 ^ ((ro & 7) << 3))] = sstC; }               \
    half8 bwl[4][2];                                                          \
    _Pragma("unroll") for (int ct = 0; ct < 4; ct++)                          \
      _Pragma("unroll") for (int ks = 0; ks < 2; ks++)                        \
        bwl[ct][ks] = *(const half8*)&Wl[((MT) * 64 + ct * 16 + lc) * 64      \
                                         + ((ks * 32 + koff) ^ swz)];         \
    f32x4 accP[2][4];                                                         \
    _Pragma("unroll") for (int rt = 0; rt < 2; rt++)                          \
      _Pragma("unroll") for (int ct = 0; ct < 4; ct++)                        \
        accP[rt][ct] = (f32x4){0.f, 0.f, 0.f, 0.f};                           \
    _Pragma("unroll") for (int ks = 0; ks < 2; ks++)                          \
      _Pragma("unroll") for (int ct = 0; ct < 4; ct++) {                      \
        accP[0][ct] = mfma16(aq[0][ks], bwl[ct][ks], accP[0][ct]);            \
        accP[1][ct] = mfma16(aq[1][ks], bwl[ct][ks], accP[1][ct]);            \
      }                                                                       \
    _Pragma("unroll") for (int rt = 0; rt < 2; rt++)                          \
      _Pragma("unroll") for (int ct = 0; ct < 4; ct++)                        \
        _Pragma("unroll") for (int r = 0; r < 4; r++) {                       \
          int i = wr + rt * 16 + rg * 4 + r;                                  \
          float val = __expf(accP[rt][ct][r] - rowm[rt][r]) * 0.0625f + 1e-4f;\
          PQ[i * 64 + ((ct * 16 + lc) ^ ((i & 7) << 3))] = (half_t)val;       \
        }                                                                     \
    _Pragma("unroll") for (int rt = 0; rt < 2; rt++)                          \
      _Pragma("unroll") for (int ct = 0; ct < 4; ct++)                        \
        accP[rt][ct] = (f32x4){0.f, 0.f, 0.f, 0.f};                           \
    _Pragma("unroll") for (int ks = 0; ks < 2; ks++)                          \
      _Pragma("unroll") for (int ct = 0; ct < 4; ct++) {                      \
        accP[0][ct] = mfma16(ak[0][ks], bwl[ct][ks], accP[0][ct]);            \
        accP[1][ct] = mfma16(ak[1][ks], bwl[ct][ks], accP[1][ct]);            \
      }                                                                       \
    _Pragma("unroll") for (int rt = 0; rt < 2; rt++)                          \
      _Pragma("unroll") for (int ct = 0; ct < 4; ct++)                        \
        _Pragma("unroll") for (int r = 0; r < 4; r++) {                       \
          int i = wr + rt * 16 + rg * 4 + r;                                  \
          float val = __expf(accP[rt][ct][r] - hnr[rt][r] - gmaxv) * 0.0625f + 1e-4f; \
          PK[i * 64 + ((ct * 16 + lc) ^ ((i & 7) << 3))] = (half_t)val;       \
        }                                                                     \
  } while (0)

#define COMPUTEPHASE() do {                                                   \
    _Pragma("unroll") for (int ks2 = 0; ks2 < 64; ks2 += 32) {                \
      int sA = (ks2 + koff) ^ swz;                                            \
      half8 a0 = *(const half8*)&PQ[(wr + lc) * 64 + sA];                     \
      half8 a1 = *(const half8*)&PQ[(wr + 16 + lc) * 64 + sA];                \
      _Pragma("unroll") for (int ct = 0; ct < 8; ct++) {                      \
        half8 b = *(const half8*)&PK[(ct * 16 + lc) * 64 + sA];               \
        accA[0][ct] = mfma16(a0, b, accA[0][ct]);                             \
        accA[1][ct] = mfma16(a1, b, accA[1][ct]);                             \
      }                                                                       \
      _Pragma("unroll") for (int cs = 0; cs < 5; cs++) {                      \
        half8 b = *(const half8*)&SST[(cs * 16 + lc) * 64 + sA];              \
        accO[0][cs] = mfma16(a0, b, accO[0][cs]);                             \
        accO[1][cs] = mfma16(a1, b, accO[1][cs]);                             \
      }                                                                       \
    } } while (0)

  LOADSST(0);
  __syncthreads();   // Wl, SST-pad-zero, nrmK visible
  float hnr[2][4];
  #pragma unroll
  for (int rt = 0; rt < 2; rt++)
    #pragma unroll
    for (int r = 0; r < 4; r++) hnr[rt][r] = nrmK[wr + rt * 16 + rg * 4 + r];

  f32x4 accA[2][8], accO[2][5];
  #pragma unroll
  for (int rt = 0; rt < 2; rt++) {
    #pragma unroll
    for (int ct = 0; ct < 8; ct++) accA[rt][ct] = (f32x4){0.f, 0.f, 0.f, 0.f};
    #pragma unroll
    for (int cs = 0; cs < 5; cs++) accO[rt][cs] = (f32x4){0.f, 0.f, 0.f, 0.f};
  }

  float4 vv0, vv1, vv2, vv3, vv4, vv5, vv6, vv7;

  // mt = 0
  STAGEPHASE(0);
  __syncthreads();
  LOADSST(1);
  COMPUTEPHASE();
  __syncthreads();
  // mt = 1
  STAGEPHASE(1);
  __syncthreads();
  LOADSST(2);
  COMPUTEPHASE();
  __syncthreads();
  // mt = 2
  STAGEPHASE(2);
  __syncthreads();
  LOADSST(3);
  COMPUTEPHASE();
  __syncthreads();
  // mt = 3
  STAGEPHASE(3);
  __syncthreads();
  {  // prefetch v during last compute phase
    const float* vb = v + nbase * 64;
    vv0 = *(const float4*)(vb + ((tid + 0 * 256) >> 4) * 64 + ((tid + 0 * 256) & 15) * 4);
    vv1 = *(const float4*)(vb + ((tid + 1 * 256) >> 4) * 64 + ((tid + 1 * 256) & 15) * 4);
    vv2 = *(const float4*)(vb + ((tid + 2 * 256) >> 4) * 64 + ((tid + 2 * 256) & 15) * 4);
    vv3 = *(const float4*)(vb + ((tid + 3 * 256) >> 4) * 64 + ((tid + 3 * 256) & 15) * 4);
    vv4 = *(const float4*)(vb + ((tid + 4 * 256) >> 4) * 64 + ((tid + 4 * 256) & 15) * 4);
    vv5 = *(const float4*)(vb + ((tid + 5 * 256) >> 4) * 64 + ((tid + 5 * 256) & 15) * 4);
    vv6 = *(const float4*)(vb + ((tid + 6 * 256) >> 4) * 64 + ((tid + 6 * 256) & 15) * 4);
    vv7 = *(const float4*)(vb + ((tid + 7 * 256) >> 4) * 64 + ((tid + 7 * 256) & 15) * 4);
  }
  COMPUTEPHASE();
  __syncthreads();

  // ---- phase 2: VT staging (swizzled) + masked A @ v_aug ----
#define PUTV(VV, E) do {                                                      \
    int l = tid + (E) * 256; int j = l >> 4, dq = (l & 15) * 4;               \
    VT[(dq + 0) * 128 + (j ^ (((dq + 0) & 7) << 3))] = (half_t)VV.x;          \
    VT[(dq + 1) * 128 + (j ^ (((dq + 1) & 7) << 3))] = (half_t)VV.y;          \
    VT[(dq + 2) * 128 + (j ^ (((dq + 2) & 7) << 3))] = (half_t)VV.z;          \
    VT[(dq + 3) * 128 + (j ^ (((dq + 3) & 7) << 3))] = (half_t)VV.w;          \
  } while (0)
  PUTV(vv0, 0); PUTV(vv1, 1); PUTV(vv2, 2); PUTV(vv3, 3);
  PUTV(vv4, 4); PUTV(vv5, 5); PUTV(vv6, 6); PUTV(vv7, 7);
  if (tid < 128) VT[64 * 128 + tid] = (half_t)1.0f;   // row 64: (64&7)=0, no swz

  #pragma unroll
  for (int h = 0; h < 2; h++) {
    #pragma unroll
    for (int rt = 0; rt < 2; rt++)
      #pragma unroll
      for (int c4 = 0; c4 < 4; c4++) {
        int ct = h * 4 + c4;
        int j = ct * 16 + lc;
        #pragma unroll
        for (int r = 0; r < 4; r++) {
          int i = wr + rt * 16 + rg * 4 + r;
          float val = (j <= i) ? accA[rt][ct][r] : 0.f;
          AS[i * 64 + ((j - h * 64) ^ ((i & 7) << 3))] = (half_t)val;
        }
      }
    if (h == 0) __syncthreads();   // VT staged by all threads
    #pragma unroll
    for (int ks2 = 0; ks2 < 64; ks2 += 32) {
      int sA = (ks2 + koff) ^ swz;
      int sV = (h * 64 + ks2 + koff) ^ swz;
      half8 a0 = *(const half8*)&AS[(wr + lc) * 64 + sA];
      half8 a1 = *(const half8*)&AS[(wr + 16 + lc) * 64 + sA];
      #pragma unroll
      for (int cs = 0; cs < 5; cs++) {
        half8 b = *(const half8*)&VT[(cs * 16 + lc) * 128 + sV];
        accO[0][cs] = mfma16(a0, b, accO[0][cs]);
        accO[1][cs] = mfma16(a1, b, accO[1][cs]);
      }
    }
  }

  // ---- epilogue: divide by den, stage to LDS f32, coalesced store ----
  __syncthreads();   // all AV MFMA reads of AS/VT done
  float* OS = (float*)sm;   // [128][68]
  #pragma unroll
  for (int rt = 0; rt < 2; rt++)
    #pragma unroll
    for (int r = 0; r < 4; r++) {
      float den = __shfl(accO[rt][4][r], (lane & 48), 64) + 1e-6f;
      float inv = 1.0f / den;
      int i = wr + rt * 16 + rg * 4 + r;
      #pragma unroll
      for (int cs = 0; cs < 4; cs++)
        OS[i * 68 + cs * 16 + lc] = accO[rt][cs][r] * inv;
    }
  __syncthreads();
  #pragma unroll
  for (int e = 0; e < 8; e++) {
    int l = tid + e * 256;            // 2048 float4s
    int row = l >> 4, c4 = (l & 15) * 4;
    float4 t4 = *(const float4*)&OS[row * 68 + c4];
    *(float4*)(out + (nbase + row) * 64 + c4) = t4;
  }
#undef LOADSST
#undef STAGEPHASE
#undef COMPUTEPHASE
#undef PUTV
}

// ============================================================================
// launcher
// ws: rowmQ f32 @0 (512KB) | spA f16 @524288 (33.3MB) | spB f16 @34603008
//     (33.3MB) | kmax u32 @68681728   -> ~68.7 MB total
// ============================================================================
extern "C" void kernel_launch(void* const* d_in, const int* in_sizes, int n_in,
                              void* d_out, int out_size, void* d_ws, size_t ws_size,
                              hipStream_t stream) {
  const float* q = (const float*)d_in[0];
  const float* k = (const float*)d_in[1];
  const float* v = (const float*)d_in[2];
  const float* omega = (const float*)d_in[3];
  float* out = (float*)d_out;
  char* ws = (char*)d_ws;

  float*  rowmQ = (float*)(ws + 0);
  half_t* spA   = (half_t*)(ws + 524288);
  half_t* spB   = (half_t*)(ws + 34603008);
  uint_t* kmax  = (uint_t*)(ws + 68681728);

  k_init<<<1, 1, 0, stream>>>(kmax);
  k_maxes<<<2048, 256, 0, stream>>>(q, k, omega, rowmQ, kmax);
  k_state<<<1024, 256, 0, stream>>>(k, v, omega, kmax, spA);
  k_prefix<<<dim3(33, 32), 256, 0, stream>>>((const uint_t*)spA, (uint_t*)spB);
  k_attn4<<<1024, 256, 0, stream>>>(q, k, v, omega, rowmQ, kmax, spB, out);
}